// Round 3
// baseline (550.794 us; speedup 1.0000x reference)
//
#include <hip/hip_runtime.h>
#include <hip/hip_fp16.h>

#define NB 4096
#define NT 400
#define NCH 42
#define NH 16
#define NT4 100  // T/4

// DPP row-rotate within 16-lane rows. Direction is self-calibrated at runtime
// by applying the same DPP to the lane index, so semantics ambiguity is moot.
#define RORI(v,K) __builtin_amdgcn_update_dpp(0, (v), 0x120+(K), 0xF, 0xF, true)
#define RORF(v,K) __int_as_float(__builtin_amdgcn_update_dpp(0, __float_as_int(v), 0x120+(K), 0xF, 0xF, true))

static __device__ __forceinline__ float fast_tanh(float x) {
  float ax = __builtin_fabsf(x);
  float e  = __expf(2.0f * ax);                       // -> +inf for large ax (safe)
  float r  = __builtin_fmaf(-2.0f, __builtin_amdgcn_rcpf(e + 1.0f), 1.0f);
  return __builtin_copysignf(r, x);
}

static __device__ __forceinline__ uint pack_h2(float a, float b) {
  __half ha = __float2half(a), hb = __float2half(b);
  return (uint)__half_as_ushort(ha) | ((uint)__half_as_ushort(hb) << 16);
}

// ---------------- Phase 1: time-parallel input projection ----------------
// P stored fp16: per (t4,b): 16 half4 (one per hidden j), contiguous 128 B.
__global__ __launch_bounds__(128) void proj0_kernel(
    const float* __restrict__ x, const float* __restrict__ Wih0,
    const float* __restrict__ bih0, const float* __restrict__ bhh0,
    uint4* __restrict__ P)
{
  __shared__ float Wl[NH * NCH];
  __shared__ float bl[NH];
  const int tid = threadIdx.x;
  for (int i = tid; i < NH * NCH; i += 128) Wl[i] = Wih0[i];
  if (tid < NH) bl[tid] = bih0[tid] + bhh0[tid];
  __syncthreads();

  const int b  = blockIdx.x;
  const int t4 = tid;
  if (t4 >= NT4) return;

  float4 acc[NH];
#pragma unroll
  for (int j = 0; j < NH; ++j) { float bb = bl[j]; acc[j] = make_float4(bb, bb, bb, bb); }

  const float* xrow = x + (size_t)b * (NCH * NT) + t4 * 4;
  // 6 chunks of 7: keep 7 dwordx4 loads in flight per chunk (MLP).
#pragma unroll
  for (int cc = 0; cc < NCH; cc += 7) {
    float4 xv[7];
#pragma unroll
    for (int u = 0; u < 7; ++u) xv[u] = *(const float4*)(xrow + (size_t)(cc + u) * NT);
#pragma unroll
    for (int u = 0; u < 7; ++u) {
#pragma unroll
      for (int j = 0; j < NH; ++j) {
        float w = Wl[j * NCH + cc + u];
        acc[j].x = __builtin_fmaf(xv[u].x, w, acc[j].x);
        acc[j].y = __builtin_fmaf(xv[u].y, w, acc[j].y);
        acc[j].z = __builtin_fmaf(xv[u].z, w, acc[j].z);
        acc[j].w = __builtin_fmaf(xv[u].w, w, acc[j].w);
      }
    }
  }

  // Pack to fp16: 8 x uint4 = 128 contiguous bytes per lane (one full line).
  uint4* Pout = P + ((size_t)t4 * NB + b) * 8;
#pragma unroll
  for (int jp = 0; jp < 8; ++jp) {
    const float4 a0 = acc[2 * jp], a1 = acc[2 * jp + 1];
    uint4 ov;
    ov.x = pack_h2(a0.x, a0.y);
    ov.y = pack_h2(a0.z, a0.w);
    ov.z = pack_h2(a1.x, a1.y);
    ov.w = pack_h2(a1.z, a1.w);
    Pout[jp] = ov;
  }
}

// ---------------- Phase 2: sequential recurrence ----------------
// 16 lanes per batch element: lane j owns hidden unit j of both layers.
// Cross-lane matvecs via DPP row_ror folded against pre-permuted weights.
__global__ __launch_bounds__(256) void rnn_seq_kernel(
    const uint2* __restrict__ P, const float* __restrict__ h0in,
    const float* __restrict__ Whh0, const float* __restrict__ Wih1,
    const float* __restrict__ Whh1, const float* __restrict__ bih1,
    const float* __restrict__ bhh1, const float* __restrict__ Wfc,
    const float* __restrict__ bfc, float* __restrict__ out)
{
  const int gtid = blockIdx.x * blockDim.x + threadIdx.x;
  const int b = gtid >> 4;
  const int j = threadIdx.x & 15;

  // Pre-permuted weights: w[k] multiplies the value DPP row_ror:k delivers.
  float w0[NH], wi1[NH], wh1[NH];
  w0[0]  = Whh0[j * NH + j];
  wi1[0] = Wih1[j * NH + j];
  wh1[0] = Whh1[j * NH + j];
#define LOADW(K) { int sj = RORI(j, K) & 15; \
  w0[K]  = Whh0[j * NH + sj]; \
  wi1[K] = Wih1[j * NH + sj]; \
  wh1[K] = Whh1[j * NH + sj]; }
  LOADW(1) LOADW(2) LOADW(3) LOADW(4) LOADW(5) LOADW(6) LOADW(7) LOADW(8)
  LOADW(9) LOADW(10) LOADW(11) LOADW(12) LOADW(13) LOADW(14) LOADW(15)
#undef LOADW
  const float b1   = bih1[j] + bhh1[j];
  const float wfc0 = Wfc[j];
  const float wfc1 = Wfc[NH + j];

  float h0 = h0in[b * NH + j];
  float h1 = h0in[(size_t)NB * NH + b * NH + j];

  const size_t pstride = (size_t)NB * NH;       // uint2 units per t4 slice
  const size_t pidx    = (size_t)b * NH + j;
  uint2 pc = P[pidx];
  uint2 pn = P[pidx + pstride];

  for (int t4 = 0; t4 < NT4; ++t4) {
    const int nx = (t4 + 2 < NT4) ? (t4 + 2) : (NT4 - 1);
    uint2 p2 = P[pidx + (size_t)nx * pstride];  // prefetch depth 2 (~8 steps of compute)

    union { uint2 u; __half2 h[2]; } cv; cv.u = pc;
    float2 f0 = __half22float2(cv.h[0]);
    float2 f1 = __half22float2(cv.h[1]);
    float pv[4] = {f0.x, f0.y, f1.x, f1.y};

#pragma unroll
    for (int q = 0; q < 4; ++q) {
      // layer 0: a = P + Whh0 . h0_prev   (two accumulators to shorten dep chain)
      float a  = __builtin_fmaf(h0, w0[0], pv[q]);
      float a2 = 0.0f;
#define L0T(K) { float hv = RORF(h0, K); \
  if ((K) & 1) a2 = __builtin_fmaf(hv, w0[K], a2); \
  else         a  = __builtin_fmaf(hv, w0[K], a); }
      L0T(1) L0T(2) L0T(3) L0T(4) L0T(5) L0T(6) L0T(7) L0T(8)
      L0T(9) L0T(10) L0T(11) L0T(12) L0T(13) L0T(14) L0T(15)
#undef L0T
      float h0n = fast_tanh(a + a2);

      // layer 1: c = b1 + Wih1 . h0n + Whh1 . h1_prev
      float c1 = __builtin_fmaf(h0n, wi1[0], b1);
      float c2 = h1 * wh1[0];
#define L1A(K) { float hv = RORF(h0n, K); \
  if ((K) & 1) c2 = __builtin_fmaf(hv, wi1[K], c2); \
  else         c1 = __builtin_fmaf(hv, wi1[K], c1); }
      L1A(1) L1A(2) L1A(3) L1A(4) L1A(5) L1A(6) L1A(7) L1A(8)
      L1A(9) L1A(10) L1A(11) L1A(12) L1A(13) L1A(14) L1A(15)
#undef L1A
#define L1B(K) { float hv = RORF(h1, K); \
  if ((K) & 1) c1 = __builtin_fmaf(hv, wh1[K], c1); \
  else         c2 = __builtin_fmaf(hv, wh1[K], c2); }
      L1B(1) L1B(2) L1B(3) L1B(4) L1B(5) L1B(6) L1B(7) L1B(8)
      L1B(9) L1B(10) L1B(11) L1B(12) L1B(13) L1B(14) L1B(15)
#undef L1B
      h1 = fast_tanh(c1 + c2);
      h0 = h0n;
    }
    pc = pn;
    pn = p2;
  }

  // FC head: out[b,n] = sum_j h1[j]*Wfc[n,j] + bfc[n]
  float v0 = h1 * wfc0;
  float v1 = h1 * wfc1;
#pragma unroll
  for (int m = 8; m >= 1; m >>= 1) {
    v0 += __shfl_xor(v0, m, 16);
    v1 += __shfl_xor(v1, m, 16);
  }
  if (j == 0) {
    float* o = out + (size_t)b * 2;
    o[0] = v0 + bfc[0];
    o[1] = v1 + bfc[1];
  }
}

extern "C" void kernel_launch(void* const* d_in, const int* in_sizes, int n_in,
                              void* d_out, int out_size, void* d_ws, size_t ws_size,
                              hipStream_t stream) {
  const float* x    = (const float*)d_in[0];
  const float* h0   = (const float*)d_in[1];
  const float* Wih0 = (const float*)d_in[2];
  const float* Whh0 = (const float*)d_in[3];
  const float* bih0 = (const float*)d_in[4];
  const float* bhh0 = (const float*)d_in[5];
  const float* Wih1 = (const float*)d_in[6];
  const float* Whh1 = (const float*)d_in[7];
  const float* bih1 = (const float*)d_in[8];
  const float* bhh1 = (const float*)d_in[9];
  const float* Wfc  = (const float*)d_in[10];
  const float* bfc  = (const float*)d_in[11];
  float* outp = (float*)d_out;

  proj0_kernel<<<NB, 128, 0, stream>>>(x, Wih0, bih0, bhh0, (uint4*)d_ws);
  rnn_seq_kernel<<<(NB * NH) / 256, 256, 0, stream>>>(
      (const uint2*)d_ws, h0, Whh0, Wih1, Whh1, bih1, bhh1, Wfc, bfc, outp);
}

// Round 4
// 543.785 us; speedup vs baseline: 1.0129x; 1.0129x over previous
//
#include <hip/hip_runtime.h>
#include <hip/hip_fp16.h>

#define NB 4096
#define NT 400
#define NCH 42
#define NH 16
#define NT4 100  // T/4

// DPP row-rotate within 16-lane rows; direction self-calibrated via RORI(j,K).
#define RORI(v,K) __builtin_amdgcn_update_dpp(0, (v), 0x120+(K), 0xF, 0xF, true)
#define RORF(v,K) __int_as_float(__builtin_amdgcn_update_dpp(0, __float_as_int(v), 0x120+(K), 0xF, 0xF, true))

static __device__ __forceinline__ float fast_tanh(float x) {
  float ax = __builtin_fabsf(x);
  float e  = __expf(2.0f * ax);                       // -> +inf for large ax (safe)
  float r  = __builtin_fmaf(-2.0f, __builtin_amdgcn_rcpf(e + 1.0f), 1.0f);
  return __builtin_copysignf(r, x);
}

static __device__ __forceinline__ uint pack_h2(float a, float b) {
  __half ha = __float2half(a), hb = __float2half(b);
  return (uint)__half_as_ushort(ha) | ((uint)__half_as_ushort(hb) << 16);
}

// ---------------- Phase 1: time-parallel input projection ----------------
// Lane owns (t4, jh): 4 time steps x 8 hidden units. Weights transposed in
// LDS (WlT[c][j]) -> 2 broadcast ds_read_b128 per c instead of 16 ds_read_b32.
// P stored fp16: per (t4,b): 16 half4 (j-major), contiguous 128 B.
__global__ __launch_bounds__(256) void proj0_kernel(
    const float* __restrict__ x, const float* __restrict__ Wih0,
    const float* __restrict__ bih0, const float* __restrict__ bhh0,
    uint4* __restrict__ P)
{
  __shared__ float WlT[NCH * NH];   // [c][j] transposed
  __shared__ float bl[NH];
  const int tid = threadIdx.x;
  for (int i = tid; i < NCH * NH; i += 256)
    WlT[i] = Wih0[(i & 15) * NCH + (i >> 4)];
  if (tid < NH) bl[tid] = bih0[tid] + bhh0[tid];
  __syncthreads();

  const int b  = blockIdx.x;
  const int jh = tid >> 7;          // 0: j 0..7, 1: j 8..15
  const int t4 = tid & 127;
  if (t4 >= NT4) return;

  float4 acc[8];                    // [jj] over the 4 time steps
#pragma unroll
  for (int jj = 0; jj < 8; ++jj) { float bb = bl[jh * 8 + jj]; acc[jj] = make_float4(bb, bb, bb, bb); }

  const float*  xrow = x + (size_t)b * (NCH * NT) + t4 * 4;
  const float4* WT4  = (const float4*)WlT;      // [c*4 + quad]

#pragma unroll
  for (int cc = 0; cc < NCH; cc += 7) {
    float4 xv[7];
#pragma unroll
    for (int u = 0; u < 7; ++u) xv[u] = *(const float4*)(xrow + (size_t)(cc + u) * NT);
#pragma unroll
    for (int u = 0; u < 7; ++u) {
      const int c = cc + u;
      float4 wA = WT4[c * 4 + jh * 2];
      float4 wB = WT4[c * 4 + jh * 2 + 1];
      float wv[8] = {wA.x, wA.y, wA.z, wA.w, wB.x, wB.y, wB.z, wB.w};
#pragma unroll
      for (int jj = 0; jj < 8; ++jj) {
        acc[jj].x = __builtin_fmaf(xv[u].x, wv[jj], acc[jj].x);
        acc[jj].y = __builtin_fmaf(xv[u].y, wv[jj], acc[jj].y);
        acc[jj].z = __builtin_fmaf(xv[u].z, wv[jj], acc[jj].z);
        acc[jj].w = __builtin_fmaf(xv[u].w, wv[jj], acc[jj].w);
      }
    }
  }

  // 4 x uint4 = 64 contiguous bytes per lane (this jh-half of the 128-B group).
  uint4* Pout = P + ((size_t)t4 * NB + b) * 8 + jh * 4;
#pragma unroll
  for (int k = 0; k < 4; ++k) {
    const float4 a0 = acc[2 * k], a1 = acc[2 * k + 1];
    uint4 ov;
    ov.x = pack_h2(a0.x, a0.y);
    ov.y = pack_h2(a0.z, a0.w);
    ov.z = pack_h2(a1.x, a1.y);
    ov.w = pack_h2(a1.z, a1.w);
    Pout[k] = ov;
  }
}

// ---------------- Phase 2: sequential recurrence ----------------
// 16 lanes per batch element; each lane runs TWO batch elements (b, b+2048)
// as independent interleaved chains to fill dependency-stall slots.
__global__ __launch_bounds__(256) void rnn_seq_kernel(
    const uint2* __restrict__ P, const float* __restrict__ h0in,
    const float* __restrict__ Whh0, const float* __restrict__ Wih1,
    const float* __restrict__ Whh1, const float* __restrict__ bih1,
    const float* __restrict__ bhh1, const float* __restrict__ Wfc,
    const float* __restrict__ bfc, float* __restrict__ out)
{
  const int gtid = blockIdx.x * blockDim.x + threadIdx.x;
  const int g = gtid >> 4;                 // 0..2047
  const int j = threadIdx.x & 15;
  const int b0 = g, bS = g + (NB / 2);

  float w0[NH], wi1[NH], wh1[NH];
  w0[0]  = Whh0[j * NH + j];
  wi1[0] = Wih1[j * NH + j];
  wh1[0] = Whh1[j * NH + j];
#define LOADW(K) { int sj = RORI(j, K) & 15; \
  w0[K]  = Whh0[j * NH + sj]; \
  wi1[K] = Wih1[j * NH + sj]; \
  wh1[K] = Whh1[j * NH + sj]; }
  LOADW(1) LOADW(2) LOADW(3) LOADW(4) LOADW(5) LOADW(6) LOADW(7) LOADW(8)
  LOADW(9) LOADW(10) LOADW(11) LOADW(12) LOADW(13) LOADW(14) LOADW(15)
#undef LOADW
  const float b1c  = bih1[j] + bhh1[j];
  const float wfc0 = Wfc[j];
  const float wfc1 = Wfc[NH + j];

  float h0A = h0in[b0 * NH + j];
  float h1A = h0in[(size_t)NB * NH + b0 * NH + j];
  float h0B = h0in[bS * NH + j];
  float h1B = h0in[(size_t)NB * NH + bS * NH + j];

  const size_t ps = (size_t)NB * NH;       // uint2 per t4 slice
  const size_t iA = (size_t)b0 * NH + j;
  const size_t iB = (size_t)bS * NH + j;
  uint2 cA = P[iA],      cB = P[iB];
  uint2 nA = P[iA + ps], nB = P[iB + ps];

  for (int t4 = 0; t4 < NT4; ++t4) {
    const int nx = (t4 + 2 < NT4) ? (t4 + 2) : (NT4 - 1);
    uint2 fA = P[iA + (size_t)nx * ps];
    uint2 fB = P[iB + (size_t)nx * ps];

    union { uint2 u; __half2 h[2]; } uA, uB;
    uA.u = cA; uB.u = cB;
    float2 a01 = __half22float2(uA.h[0]), a23 = __half22float2(uA.h[1]);
    float2 b01 = __half22float2(uB.h[0]), b23 = __half22float2(uB.h[1]);
    float pvA[4] = {a01.x, a01.y, a23.x, a23.y};
    float pvB[4] = {b01.x, b01.y, b23.x, b23.y};

#pragma unroll
    for (int q = 0; q < 4; ++q) {
      // ---- layer 0, chains A and B interleaved ----
      float aA = __builtin_fmaf(h0A, w0[0], pvA[q]), a2A = 0.0f;
      float aB = __builtin_fmaf(h0B, w0[0], pvB[q]), a2B = 0.0f;
#define L0T(K) { float hvA = RORF(h0A, K); float hvB = RORF(h0B, K); \
  if ((K) & 1) { a2A = __builtin_fmaf(hvA, w0[K], a2A); a2B = __builtin_fmaf(hvB, w0[K], a2B); } \
  else         { aA  = __builtin_fmaf(hvA, w0[K], aA);  aB  = __builtin_fmaf(hvB, w0[K], aB);  } }
      L0T(1) L0T(2) L0T(3) L0T(4) L0T(5) L0T(6) L0T(7) L0T(8)
      L0T(9) L0T(10) L0T(11) L0T(12) L0T(13) L0T(14) L0T(15)
#undef L0T
      float h0nA = fast_tanh(aA + a2A);
      float h0nB = fast_tanh(aB + a2B);

      // ---- layer 1 ----
      float c1A = __builtin_fmaf(h0nA, wi1[0], b1c), c2A = h1A * wh1[0];
      float c1B = __builtin_fmaf(h0nB, wi1[0], b1c), c2B = h1B * wh1[0];
#define L1A(K) { float hvA = RORF(h0nA, K); float hvB = RORF(h0nB, K); \
  if ((K) & 1) { c2A = __builtin_fmaf(hvA, wi1[K], c2A); c2B = __builtin_fmaf(hvB, wi1[K], c2B); } \
  else         { c1A = __builtin_fmaf(hvA, wi1[K], c1A); c1B = __builtin_fmaf(hvB, wi1[K], c1B); } }
      L1A(1) L1A(2) L1A(3) L1A(4) L1A(5) L1A(6) L1A(7) L1A(8)
      L1A(9) L1A(10) L1A(11) L1A(12) L1A(13) L1A(14) L1A(15)
#undef L1A
#define L1B(K) { float hvA = RORF(h1A, K); float hvB = RORF(h1B, K); \
  if ((K) & 1) { c1A = __builtin_fmaf(hvA, wh1[K], c1A); c1B = __builtin_fmaf(hvB, wh1[K], c1B); } \
  else         { c2A = __builtin_fmaf(hvA, wh1[K], c2A); c2B = __builtin_fmaf(hvB, wh1[K], c2B); } }
      L1B(1) L1B(2) L1B(3) L1B(4) L1B(5) L1B(6) L1B(7) L1B(8)
      L1B(9) L1B(10) L1B(11) L1B(12) L1B(13) L1B(14) L1B(15)
#undef L1B
      h1A = fast_tanh(c1A + c2A);
      h1B = fast_tanh(c1B + c2B);
      h0A = h0nA;
      h0B = h0nB;
    }
    cA = nA; cB = nB;
    nA = fA; nB = fB;
  }

  // FC head for both chains
  float v0A = h1A * wfc0, v1A = h1A * wfc1;
  float v0B = h1B * wfc0, v1B = h1B * wfc1;
#pragma unroll
  for (int m = 8; m >= 1; m >>= 1) {
    v0A += __shfl_xor(v0A, m, 16);
    v1A += __shfl_xor(v1A, m, 16);
    v0B += __shfl_xor(v0B, m, 16);
    v1B += __shfl_xor(v1B, m, 16);
  }
  if (j == 0) {
    float* oA = out + (size_t)b0 * 2;
    float* oB = out + (size_t)bS * 2;
    oA[0] = v0A + bfc[0];
    oA[1] = v1A + bfc[1];
    oB[0] = v0B + bfc[0];
    oB[1] = v1B + bfc[1];
  }
}

extern "C" void kernel_launch(void* const* d_in, const int* in_sizes, int n_in,
                              void* d_out, int out_size, void* d_ws, size_t ws_size,
                              hipStream_t stream) {
  const float* x    = (const float*)d_in[0];
  const float* h0   = (const float*)d_in[1];
  const float* Wih0 = (const float*)d_in[2];
  const float* Whh0 = (const float*)d_in[3];
  const float* bih0 = (const float*)d_in[4];
  const float* bhh0 = (const float*)d_in[5];
  const float* Wih1 = (const float*)d_in[6];
  const float* Whh1 = (const float*)d_in[7];
  const float* bih1 = (const float*)d_in[8];
  const float* bhh1 = (const float*)d_in[9];
  const float* Wfc  = (const float*)d_in[10];
  const float* bfc  = (const float*)d_in[11];
  float* outp = (float*)d_out;

  proj0_kernel<<<NB, 256, 0, stream>>>(x, Wih0, bih0, bhh0, (uint4*)d_ws);
  rnn_seq_kernel<<<(NB / 2 * NH) / 256, 256, 0, stream>>>(
      (const uint2*)d_ws, h0, Whh0, Wih1, Whh1, bih1, bhh1, Wfc, bfc, outp);
}

// Round 5
// 539.438 us; speedup vs baseline: 1.0211x; 1.0081x over previous
//
#include <hip/hip_runtime.h>
#include <hip/hip_fp16.h>

#define NB 4096
#define NT 400
#define NCH 42
#define NH 16
#define NT4 100  // T/4

// DPP row-rotate within 16-lane rows; direction self-calibrated via RORI(j,K).
#define RORI(v,K) __builtin_amdgcn_update_dpp(0, (v), 0x120+(K), 0xF, 0xF, true)
#define RORF(v,K) __int_as_float(__builtin_amdgcn_update_dpp(0, __float_as_int(v), 0x120+(K), 0xF, 0xF, true))

// tanh(x) = 1 - 2/(exp(2x)+1): exact at both infinities, no abs/copysign.
static __device__ __forceinline__ float fast_tanh(float x) {
  float e = __expf(2.0f * x);                        // +inf / 0 at extremes: safe
  return __builtin_fmaf(-2.0f, __builtin_amdgcn_rcpf(e + 1.0f), 1.0f);
}

static __device__ __forceinline__ uint pack_h2(float a, float b) {
  __half ha = __float2half(a), hb = __float2half(b);
  return (uint)__half_as_ushort(ha) | ((uint)__half_as_ushort(hb) << 16);
}

// ---------------- Phase 1: time-parallel input projection ----------------
// (unchanged from round 4 for attribution)
__global__ __launch_bounds__(256) void proj0_kernel(
    const float* __restrict__ x, const float* __restrict__ Wih0,
    const float* __restrict__ bih0, const float* __restrict__ bhh0,
    uint4* __restrict__ P)
{
  __shared__ float WlT[NCH * NH];   // [c][j] transposed
  __shared__ float bl[NH];
  const int tid = threadIdx.x;
  for (int i = tid; i < NCH * NH; i += 256)
    WlT[i] = Wih0[(i & 15) * NCH + (i >> 4)];
  if (tid < NH) bl[tid] = bih0[tid] + bhh0[tid];
  __syncthreads();

  const int b  = blockIdx.x;
  const int jh = tid >> 7;          // 0: j 0..7, 1: j 8..15
  const int t4 = tid & 127;
  if (t4 >= NT4) return;

  float4 acc[8];
#pragma unroll
  for (int jj = 0; jj < 8; ++jj) { float bb = bl[jh * 8 + jj]; acc[jj] = make_float4(bb, bb, bb, bb); }

  const float*  xrow = x + (size_t)b * (NCH * NT) + t4 * 4;
  const float4* WT4  = (const float4*)WlT;

#pragma unroll
  for (int cc = 0; cc < NCH; cc += 7) {
    float4 xv[7];
#pragma unroll
    for (int u = 0; u < 7; ++u) xv[u] = *(const float4*)(xrow + (size_t)(cc + u) * NT);
#pragma unroll
    for (int u = 0; u < 7; ++u) {
      const int c = cc + u;
      float4 wA = WT4[c * 4 + jh * 2];
      float4 wB = WT4[c * 4 + jh * 2 + 1];
      float wv[8] = {wA.x, wA.y, wA.z, wA.w, wB.x, wB.y, wB.z, wB.w};
#pragma unroll
      for (int jj = 0; jj < 8; ++jj) {
        acc[jj].x = __builtin_fmaf(xv[u].x, wv[jj], acc[jj].x);
        acc[jj].y = __builtin_fmaf(xv[u].y, wv[jj], acc[jj].y);
        acc[jj].z = __builtin_fmaf(xv[u].z, wv[jj], acc[jj].z);
        acc[jj].w = __builtin_fmaf(xv[u].w, wv[jj], acc[jj].w);
      }
    }
  }

  uint4* Pout = P + ((size_t)t4 * NB + b) * 8 + jh * 4;
#pragma unroll
  for (int k = 0; k < 4; ++k) {
    const float4 a0 = acc[2 * k], a1 = acc[2 * k + 1];
    uint4 ov;
    ov.x = pack_h2(a0.x, a0.y);
    ov.y = pack_h2(a0.z, a0.w);
    ov.z = pack_h2(a1.x, a1.y);
    ov.w = pack_h2(a1.z, a1.w);
    Pout[k] = ov;
  }
}

// ---------------- Phase 2: layer-pipelined recurrence ----------------
// Block = 128 threads = 2 waves, 4 batch elements per block.
// wave0: layer-0 chains (reads P, writes h0 to LDS double-buffer).
// wave1: layer-1 chains one step behind (reads h0 from LDS) + FC head.
// One __syncthreads per time step. 1024 blocks -> 2048 waves = 2/SIMD.
__global__ __launch_bounds__(128) void rnn_seq_kernel(
    const uint2* __restrict__ P, const float* __restrict__ h0in,
    const float* __restrict__ Whh0, const float* __restrict__ Wih1,
    const float* __restrict__ Whh1, const float* __restrict__ bih1,
    const float* __restrict__ bhh1, const float* __restrict__ Wfc,
    const float* __restrict__ bfc, float* __restrict__ out)
{
  __shared__ float h0buf[2 * 64];          // [t&1][grp*16+j]
  const int wid  = threadIdx.x >> 6;       // 0: layer-0 wave, 1: layer-1 wave
  const int lane = threadIdx.x & 63;
  const int grp  = lane >> 4;
  const int j    = lane & 15;
  const int b    = blockIdx.x * 4 + grp;

  // Pre-permuted weights (w[k] multiplies the value DPP row_ror:k delivers).
  float w0[NH], wi1[NH], wh1[NH];
  w0[0]  = Whh0[j * NH + j];
  wi1[0] = Wih1[j * NH + j];
  wh1[0] = Whh1[j * NH + j];
#define LOADW(K) { int sj = RORI(j, K) & 15; \
  w0[K]  = Whh0[j * NH + sj]; \
  wi1[K] = Wih1[j * NH + sj]; \
  wh1[K] = Whh1[j * NH + sj]; }
  LOADW(1) LOADW(2) LOADW(3) LOADW(4) LOADW(5) LOADW(6) LOADW(7) LOADW(8)
  LOADW(9) LOADW(10) LOADW(11) LOADW(12) LOADW(13) LOADW(14) LOADW(15)
#undef LOADW
  const float b1c  = bih1[j] + bhh1[j];
  const float wfc0 = Wfc[j];
  const float wfc1 = Wfc[NH + j];

  float h0 = h0in[b * NH + j];                            // layer-0 state (wave0)
  float h1 = h0in[(size_t)NB * NH + b * NH + j];          // layer-1 state (wave1)

  const size_t ps   = (size_t)NB * NH;     // uint2 per t4 slice
  const size_t pidx = (size_t)b * NH + j;
  uint2 pc, pn;
  if (wid == 0) { pc = P[pidx]; pn = P[pidx + ps]; }

  for (int t4 = 0; t4 < NT4; ++t4) {
    uint2 p2;
    float pv[4];
    if (wid == 0) {
      const int nx = (t4 + 2 < NT4) ? (t4 + 2) : (NT4 - 1);
      p2 = P[pidx + (size_t)nx * ps];
      union { uint2 u; __half2 h[2]; } cv; cv.u = pc;
      float2 f0 = __half22float2(cv.h[0]);
      float2 f1 = __half22float2(cv.h[1]);
      pv[0] = f0.x; pv[1] = f0.y; pv[2] = f1.x; pv[3] = f1.y;
    }

#pragma unroll
    for (int q = 0; q < 4; ++q) {
      if (wid == 0) {
        // ---- layer 0, step t = 4*t4+q ----
        float a1 = __builtin_fmaf(h0, w0[0], pv[q]);
        float a2 = 0.0f, a3 = 0.0f;
#define L0T(K) { float hv = RORF(h0, K); \
  if      ((K) % 3 == 0) a1 = __builtin_fmaf(hv, w0[K], a1); \
  else if ((K) % 3 == 1) a2 = __builtin_fmaf(hv, w0[K], a2); \
  else                   a3 = __builtin_fmaf(hv, w0[K], a3); }
        L0T(1) L0T(2) L0T(3) L0T(4) L0T(5) L0T(6) L0T(7) L0T(8)
        L0T(9) L0T(10) L0T(11) L0T(12) L0T(13) L0T(14) L0T(15)
#undef L0T
        h0 = fast_tanh(a1 + (a2 + a3));
        h0buf[(q & 1) * 64 + lane] = h0;   // (4*t4+q)&1 == q&1
      } else {
        // ---- layer 1, step t-1 = 4*t4+q-1 ----
        if (t4 > 0 || q > 0) {
          float hp = h0buf[((q + 1) & 1) * 64 + lane];   // h0(t-1), settled last barrier
          // Whh1 . h1 first (independent of hp -> hides LDS latency)
          float c2 = h1 * wh1[0];
          float c3 = 0.0f;
          float c1 = __builtin_fmaf(hp, wi1[0], b1c);
#define L1B(K) { float hv = RORF(h1, K); \
  if ((K) & 1) c2 = __builtin_fmaf(hv, wh1[K], c2); \
  else         c3 = __builtin_fmaf(hv, wh1[K], c3); }
          L1B(1) L1B(2) L1B(3) L1B(4) L1B(5) L1B(6) L1B(7) L1B(8)
          L1B(9) L1B(10) L1B(11) L1B(12) L1B(13) L1B(14) L1B(15)
#undef L1B
#define L1A(K) { float hv = RORF(hp, K); \
  if ((K) & 1) c1 = __builtin_fmaf(hv, wi1[K], c1); \
  else         c3 = __builtin_fmaf(hv, wi1[K], c3); }
          L1A(1) L1A(2) L1A(3) L1A(4) L1A(5) L1A(6) L1A(7) L1A(8)
          L1A(9) L1A(10) L1A(11) L1A(12) L1A(13) L1A(14) L1A(15)
#undef L1A
          h1 = fast_tanh((c1 + c2) + c3);
        }
      }
      __syncthreads();
    }
    if (wid == 0) { pc = pn; pn = p2; }
  }

  // Final layer-1 step: t-1 = 399 (h0(399) is in buf[1], settled by last barrier).
  if (wid == 1) {
    float hp = h0buf[1 * 64 + lane];
    float c2 = h1 * wh1[0];
    float c3 = 0.0f;
    float c1 = __builtin_fmaf(hp, wi1[0], b1c);
#define L1B(K) { float hv = RORF(h1, K); \
  if ((K) & 1) c2 = __builtin_fmaf(hv, wh1[K], c2); \
  else         c3 = __builtin_fmaf(hv, wh1[K], c3); }
    L1B(1) L1B(2) L1B(3) L1B(4) L1B(5) L1B(6) L1B(7) L1B(8)
    L1B(9) L1B(10) L1B(11) L1B(12) L1B(13) L1B(14) L1B(15)
#undef L1B
#define L1A(K) { float hv = RORF(hp, K); \
  if ((K) & 1) c1 = __builtin_fmaf(hv, wi1[K], c1); \
  else         c3 = __builtin_fmaf(hv, wi1[K], c3); }
    L1A(1) L1A(2) L1A(3) L1A(4) L1A(5) L1A(6) L1A(7) L1A(8)
    L1A(9) L1A(10) L1A(11) L1A(12) L1A(13) L1A(14) L1A(15)
#undef L1A
    h1 = fast_tanh((c1 + c2) + c3);

    // FC head
    float v0 = h1 * wfc0;
    float v1 = h1 * wfc1;
#pragma unroll
    for (int m = 8; m >= 1; m >>= 1) {
      v0 += __shfl_xor(v0, m, 16);
      v1 += __shfl_xor(v1, m, 16);
    }
    if (j == 0) {
      float* o = out + (size_t)b * 2;
      o[0] = v0 + bfc[0];
      o[1] = v1 + bfc[1];
    }
  }
}

extern "C" void kernel_launch(void* const* d_in, const int* in_sizes, int n_in,
                              void* d_out, int out_size, void* d_ws, size_t ws_size,
                              hipStream_t stream) {
  const float* x    = (const float*)d_in[0];
  const float* h0   = (const float*)d_in[1];
  const float* Wih0 = (const float*)d_in[2];
  const float* Whh0 = (const float*)d_in[3];
  const float* bih0 = (const float*)d_in[4];
  const float* bhh0 = (const float*)d_in[5];
  const float* Wih1 = (const float*)d_in[6];
  const float* Whh1 = (const float*)d_in[7];
  const float* bih1 = (const float*)d_in[8];
  const float* bhh1 = (const float*)d_in[9];
  const float* Wfc  = (const float*)d_in[10];
  const float* bfc  = (const float*)d_in[11];
  float* outp = (float*)d_out;

  proj0_kernel<<<NB, 256, 0, stream>>>(x, Wih0, bih0, bhh0, (uint4*)d_ws);
  rnn_seq_kernel<<<NB / 4, 128, 0, stream>>>(
      (const uint2*)d_ws, h0, Whh0, Wih1, Whh1, bih1, bhh1, Wfc, bfc, outp);
}